// Round 1
// 123.062 us; speedup vs baseline: 1.0773x; 1.0773x over previous
//
#include <hip/hip_runtime.h>

typedef __attribute__((ext_vector_type(8))) short short8;
typedef __attribute__((ext_vector_type(4))) float float4v;
typedef __attribute__((ext_vector_type(4))) unsigned short us4;

namespace {
constexpr int NG   = 16;
constexpr int LSEQ = 4096;
constexpr int CIN  = 1024;
constexpr int IPG  = 64;
constexpr int OPG  = 64;
constexpr int KT   = 5;
constexpr int ROWS = 128;                 // rows per chunk
constexpr int CH   = 2;                   // chunks per block (double-buffered)
constexpr int SIN_STRIDE = 72;            // shorts; 144 B rows (16B aligned)
constexpr int SIN_ROWS   = ROWS + KT - 1; // 132
constexpr int KSTEPS = 10;                // 320 K / 32
constexpr size_t WFRAG_SHORTS = (size_t)NG * 4 * KSTEPS * 512;  // 327,680
constexpr size_t WFRAG_BYTES  = WFRAG_SHORTS * 2;               // 655,360
constexpr size_t MASK_BYTES   = (size_t)4 * LSEQ;               // 16,384
}

__device__ __forceinline__ unsigned short f2bf(float f) {
  unsigned int u = __builtin_bit_cast(unsigned int, f);
  u += 0x7fffu + ((u >> 16) & 1u);   // RNE (inputs finite)
  return (unsigned short)(u >> 16);
}

// ---------------- prep: W (16,64,64,5) fp32 -> d_ws bf16 in B-frag layout ----
__global__ __launch_bounds__(256) void wprep(const float* __restrict__ gwt,
                                             unsigned short* __restrict__ wfrag) {
  const int u = blockIdx.x * 256 + threadIdx.x;           // 40960 threads
  const int E    = u * 8;
  const int tile = E >> 9;
  const int w9   = E & 511;
  const int n    = w9 >> 5;
  const int quad = (w9 & 31) >> 3;
  const int ks   = tile % KSTEPS;
  const int tt   = tile / KSTEPS;
  const int t    = tt & 3;
  const int g    = tt >> 2;
  const int tap  = ks >> 1;
  const int h    = ks & 1;
  const int o    = t * 16 + n;
  const float* src = gwt + (((size_t)(g * 64 + o) * 64) + h * 32 + quad * 8) * KT + tap;
  short8 v;
  #pragma unroll
  for (int j = 0; j < 8; ++j)
    v[j] = (short)f2bf(src[j * KT]);
  *(short8*)(wfrag + E) = v;
}

// ---------------- prep: masks, one 5-bit byte per (b,l) row ------------------
__global__ __launch_bounds__(256) void mprep(const int* __restrict__ gpos,
                                             unsigned char* __restrict__ gmask) {
  const int id = blockIdx.x * 256 + threadIdx.x;   // 16384 threads
  const int b  = id >> 12;
  const int l  = id & (LSEQ - 1);
  const int base = b * LSEQ;
  const int pc = gpos[base + l];
  unsigned int mbits = 0;
  #pragma unroll
  for (int tap = 0; tap < KT; ++tap) {
    const int lsrc = l + tap - 2;
    int ok = 0;
    if (lsrc >= 0 && lsrc < LSEQ)
      ok = (gpos[base + lsrc] == pc + (tap - 2));
    mbits |= (unsigned int)ok << tap;
  }
  gmask[id] = (unsigned char)mbits;
}

// ---------------- main v2: 2 chunks/block, dbuf LDS, batched reg staging ----
__global__ __launch_bounds__(256, 4) void mconv_main2(
    const float* __restrict__ gin,            // (4,4096,1024) fp32
    const unsigned char* __restrict__ gmask,  // (4,4096) mask bytes
    const unsigned short* __restrict__ wfrag, // bf16 frag buffer
    float* __restrict__ gout) {               // (4,4096,16,64) fp32
  __shared__ __align__(16) unsigned short sIn[2][SIN_ROWS * SIN_STRIDE]; // 38,016 B

  const int tid  = threadIdx.x;
  const int wv   = tid >> 6;
  const int lane = tid & 63;
  const int quad = lane >> 4;
  const int l16  = lane & 15;
  const int wm   = wv & 1;        // M half: rows [wm*64, wm*64+64)
  const int wn   = wv >> 1;       // N half: cols [wn*32, wn*32+32)

  const int g  = blockIdx.y;
  const int b  = blockIdx.z;
  const int l0 = blockIdx.x * (ROWS * CH);
  const int bL = b * LSEQ;

  const float* ginb = gin + (size_t)bL * CIN + g * IPG;

  // ---- batched register staging (T14): issue all loads, convert+write later
  float4v st[9];
  auto issue = [&](int l0c) {
    #pragma unroll
    for (int k = 0; k < 9; ++k) {
      const int u = tid + k * 256;
      if (u < SIN_ROWS * 16) {
        const int r  = u >> 4;
        const int c4 = u & 15;
        const int l  = l0c - 2 + r;
        float4v v = {0.f, 0.f, 0.f, 0.f};
        if (l >= 0 && l < LSEQ)
          v = *(const float4v*)(ginb + (size_t)l * CIN + c4 * 4);
        st[k] = v;
      }
    }
  };
  auto stage_write = [&](int bsel) {
    #pragma unroll
    for (int k = 0; k < 9; ++k) {
      const int u = tid + k * 256;
      if (u < SIN_ROWS * 16) {
        const int r  = u >> 4;
        const int c4 = u & 15;
        const int p  = (c4 * 4 + ((r & 3) << 4)) & 63;   // column swizzle
        us4 w;
        w[0] = f2bf(st[k][0]); w[1] = f2bf(st[k][1]);
        w[2] = f2bf(st[k][2]); w[3] = f2bf(st[k][3]);
        *(us4*)(&sIn[bsel][r * SIN_STRIDE + p]) = w;
      }
    }
  };

  // ---- masks for both chunks, loaded early (16 KB array, L2-hot)
  int mb0[4], mb1[4];
  #pragma unroll
  for (int mt = 0; mt < 4; ++mt) {
    const int rr = wm * 64 + mt * 16 + l16;
    mb0[mt] = gmask[bL + l0 + rr];
    mb1[mt] = gmask[bL + l0 + ROWS + rr];
  }

  // ---- B-frag bases (chunk-invariant)
  const int laneoff = l16 * 32 + quad * 8;
  const unsigned short* wb0 = wfrag + (size_t)((g * 4 + wn * 2) * KSTEPS) * 512 + laneoff;
  const unsigned short* wb1 = wb0 + (size_t)KSTEPS * 512;
  const short8 zero8 = {0, 0, 0, 0, 0, 0, 0, 0};
  const float4v zf = {0.f, 0.f, 0.f, 0.f};

  auto compute_store = [&](int bsel, int l0c, const int* mb) {
    float4v acc[4][2];
    #pragma unroll
    for (int mt = 0; mt < 4; ++mt) { acc[mt][0] = zf; acc[mt][1] = zf; }
    short8 bc0 = *(const short8*)(wb0);
    short8 bc1 = *(const short8*)(wb1);
    #pragma unroll 2
    for (int ks = 0; ks < KSTEPS; ++ks) {
      const int ksn = (ks + 1 < KSTEPS) ? ks + 1 : KSTEPS - 1;
      short8 bn0 = *(const short8*)(wb0 + ksn * 512);
      short8 bn1 = *(const short8*)(wb1 + ksn * 512);
      const int tap = ks >> 1;
      const int h   = ks & 1;
      const int s   = h * 32 + quad * 8;
      #pragma unroll
      for (int mt = 0; mt < 4; ++mt) {
        const int r  = wm * 64 + mt * 16 + l16 + tap;     // sIn row (halo-offset)
        const int sp = (s + ((r & 3) << 4)) & 63;
        short8 a = *(const short8*)(&sIn[bsel][r * SIN_STRIDE + sp]);
        if (!((mb[mt] >> tap) & 1)) a = zero8;
        acc[mt][0] = __builtin_amdgcn_mfma_f32_16x16x32_bf16(a, bc0, acc[mt][0], 0, 0, 0);
        acc[mt][1] = __builtin_amdgcn_mfma_f32_16x16x32_bf16(a, bc1, acc[mt][1], 0, 0, 0);
      }
      bc0 = bn0; bc1 = bn1;
    }
    // epilogue: C/D layout col=l16, row=quad*4+reg
    #pragma unroll
    for (int mt = 0; mt < 4; ++mt) {
      const int lrow = l0c + wm * 64 + mt * 16 + quad * 4;
      #pragma unroll
      for (int reg = 0; reg < 4; ++reg) {
        float* orow = gout + (size_t)(bL + lrow + reg) * CIN + g * OPG + wn * 32;
        orow[l16]      = acc[mt][0][reg];
        orow[16 + l16] = acc[mt][1][reg];
      }
    }
  };

  // ---- pipeline: stage(0) | [issue(1) ; compute(0) ; write(1)] | compute(1)
  issue(l0);
  stage_write(0);
  asm volatile("s_waitcnt lgkmcnt(0)" ::: "memory");
  __builtin_amdgcn_s_barrier();

  issue(l0 + ROWS);                 // chunk-1 loads in flight over chunk-0 compute
  compute_store(0, l0, mb0);
  stage_write(1);                   // vmcnt wait happens here, after compute
  asm volatile("s_waitcnt lgkmcnt(0)" ::: "memory");
  __builtin_amdgcn_s_barrier();

  compute_store(1, l0 + ROWS, mb1);
}

// ---------------- tier-2 main (previous kernel, used if ws fits wfrag only) --
__global__ __launch_bounds__(256, 4) void mconv_main(
    const float* __restrict__ gin,
    const int* __restrict__ gpos,
    const unsigned short* __restrict__ wfrag,
    float* __restrict__ gout) {
  __shared__ __align__(16) unsigned short sIn[SIN_ROWS * SIN_STRIDE];
  __shared__ unsigned char sMaskB[ROWS];

  const int tid  = threadIdx.x;
  const int wv   = tid >> 6;
  const int lane = tid & 63;
  const int quad = lane >> 4;
  const int l16  = lane & 15;
  const int wm   = wv & 1;
  const int wn   = wv >> 1;

  const int g  = blockIdx.y;
  const int b  = blockIdx.z;
  const int l0 = blockIdx.x * ROWS;
  const int bL = b * LSEQ;

  for (int u = tid; u < SIN_ROWS * 16; u += 256) {
    const int r  = u >> 4;
    const int c4 = u & 15;
    const int l  = l0 - 2 + r;
    us4 w = {0, 0, 0, 0};
    if (l >= 0 && l < LSEQ) {
      float4v v = *(const float4v*)(gin + (size_t)(bL + l) * CIN + g * IPG + c4 * 4);
      w[0] = f2bf(v[0]); w[1] = f2bf(v[1]); w[2] = f2bf(v[2]); w[3] = f2bf(v[3]);
    }
    const int p = (c4 * 4 + ((r & 3) << 4)) & 63;
    *(us4*)(&sIn[r * SIN_STRIDE + p]) = w;
  }

  if (tid < ROWS) {
    const int l = l0 + tid;
    const int pc = gpos[bL + l];
    unsigned int mbits = 0;
    #pragma unroll
    for (int tap = 0; tap < KT; ++tap) {
      const int lsrc = l + tap - 2;
      int ok = 0;
      if (lsrc >= 0 && lsrc < LSEQ)
        ok = (gpos[bL + lsrc] == pc + (tap - 2));
      mbits |= (unsigned int)ok << tap;
    }
    sMaskB[tid] = (unsigned char)mbits;
  }
  __syncthreads();

  int mb[4];
  #pragma unroll
  for (int mt = 0; mt < 4; ++mt)
    mb[mt] = sMaskB[wm * 64 + mt * 16 + l16];

  const int laneoff = l16 * 32 + quad * 8;
  const unsigned short* wb0 = wfrag + (size_t)((g * 4 + wn * 2) * KSTEPS) * 512 + laneoff;
  const unsigned short* wb1 = wb0 + (size_t)KSTEPS * 512;

  const short8 zero8 = {0, 0, 0, 0, 0, 0, 0, 0};
  const float4v zf = {0.f, 0.f, 0.f, 0.f};
  float4v acc[4][2];
  #pragma unroll
  for (int mt = 0; mt < 4; ++mt) { acc[mt][0] = zf; acc[mt][1] = zf; }

  short8 bc0 = *(const short8*)(wb0);
  short8 bc1 = *(const short8*)(wb1);

  #pragma unroll 2
  for (int ks = 0; ks < KSTEPS; ++ks) {
    const int ksn = (ks + 1 < KSTEPS) ? ks + 1 : KSTEPS - 1;
    short8 bn0 = *(const short8*)(wb0 + ksn * 512);
    short8 bn1 = *(const short8*)(wb1 + ksn * 512);
    const int tap = ks >> 1;
    const int h   = ks & 1;
    const int s   = h * 32 + quad * 8;
    #pragma unroll
    for (int mt = 0; mt < 4; ++mt) {
      const int r  = wm * 64 + mt * 16 + l16 + tap;
      const int sp = (s + ((r & 3) << 4)) & 63;
      short8 a = *(const short8*)(&sIn[r * SIN_STRIDE + sp]);
      if (!((mb[mt] >> tap) & 1)) a = zero8;
      acc[mt][0] = __builtin_amdgcn_mfma_f32_16x16x32_bf16(a, bc0, acc[mt][0], 0, 0, 0);
      acc[mt][1] = __builtin_amdgcn_mfma_f32_16x16x32_bf16(a, bc1, acc[mt][1], 0, 0, 0);
    }
    bc0 = bn0; bc1 = bn1;
  }

  #pragma unroll
  for (int mt = 0; mt < 4; ++mt) {
    const int lrow = l0 + wm * 64 + mt * 16 + quad * 4;
    #pragma unroll
    for (int reg = 0; reg < 4; ++reg) {
      float* orow = gout + (size_t)(bL + lrow + reg) * CIN + g * OPG + wn * 32;
      orow[l16]      = acc[mt][0][reg];
      orow[16 + l16] = acc[mt][1][reg];
    }
  }
}

// ---------------- fallback (known-good R3 kernel, used if ws too small) -----
namespace fb {
constexpr int ROWS_PER_CHUNK = 128;
constexpr int CHUNKS = 4;
constexpr int ROWS_PER_BLOCK = 512;
constexpr int SW_STRIDE  = 328;
constexpr int FSIN_STRIDE = 72;
constexpr int FSIN_ROWS   = 132;
}

__global__ __launch_bounds__(256, 2) void mconv_f32_mfma(
    const float* __restrict__ gin, const int* __restrict__ gpos,
    const float* __restrict__ gwt, float* __restrict__ gout) {
  using namespace fb;
  __shared__ __align__(16) unsigned short sW[OPG * SW_STRIDE];
  __shared__ __align__(16) unsigned short sIn[FSIN_ROWS * FSIN_STRIDE];
  __shared__ unsigned char sMask[ROWS_PER_CHUNK * KT];

  const int tid  = threadIdx.x;
  const int wave = tid >> 6;
  const int lane = tid & 63;
  const int quad = lane >> 4;
  const int l16  = lane & 15;
  const int g  = blockIdx.y;
  const int b  = blockIdx.z;
  const int tile0 = blockIdx.x * ROWS_PER_BLOCK;
  const int bL = b * LSEQ;

  {
    const float* wg = gwt + (size_t)g * (OPG * IPG * KT);
    for (int u = tid; u < (OPG * IPG * KT) / 4; u += 256) {
      const int base = u * 4;
      float4v v = *(const float4v*)(wg + base);
      int o = base / (IPG * KT);
      int r = base - o * (IPG * KT);
      int i = r / KT;
      int k = r - i * KT;
      int addr = o * SW_STRIDE + k * IPG + i;
      #pragma unroll
      for (int t = 0; t < 4; ++t) {
        sW[addr] = f2bf(v[t]);
        ++k; addr += IPG;
        if (k == KT) { k = 0; ++i; addr -= KT * IPG - 1; }
      }
    }
  }
  const short8 zero8 = {0,0,0,0,0,0,0,0};
  const float4v zf = {0.f,0.f,0.f,0.f};
  for (int ch = 0; ch < CHUNKS; ++ch) {
    const int l0 = tile0 + ch * ROWS_PER_CHUNK;
    __syncthreads();
    for (int t = tid; t < ROWS_PER_CHUNK * KT; t += 256) {
      const int lr = t / KT, tap = t - lr * KT, l = l0 + lr, lsrc = l + tap - 2;
      int ok = 0;
      if (lsrc >= 0 && lsrc < LSEQ) ok = (gpos[bL + lsrc] == gpos[bL + l] + (tap - 2));
      sMask[t] = (unsigned char)ok;
    }
    for (int u = tid; u < FSIN_ROWS * 16; u += 256) {
      const int r = u >> 4, c4 = u & 15, l = l0 - 2 + r;
      us4 w = {0,0,0,0};
      if (l >= 0 && l < LSEQ) {
        float4v v = *(const float4v*)(gin + (size_t)(bL + l) * CIN + g * IPG + c4 * 4);
        w[0]=f2bf(v[0]); w[1]=f2bf(v[1]); w[2]=f2bf(v[2]); w[3]=f2bf(v[3]);
      }
      *(us4*)(&sIn[r * FSIN_STRIDE + c4 * 4]) = w;
    }
    __syncthreads();
    float4v acc[2][4];
    #pragma unroll
    for (int mm = 0; mm < 2; ++mm)
      #pragma unroll
      for (int nt = 0; nt < 4; ++nt) acc[mm][nt] = zf;
    const int m0 = wave * 32 + l16, m1 = m0 + 16;
    #pragma unroll
    for (int tap = 0; tap < KT; ++tap) {
      const bool msk0 = sMask[m0 * KT + tap] != 0;
      const bool msk1 = sMask[m1 * KT + tap] != 0;
      #pragma unroll
      for (int h = 0; h < 2; ++h) {
        const int kk = tap * IPG + h * 32 + quad * 8;
        const short8 b0 = *(const short8*)(&sW[(0*16 + l16) * SW_STRIDE + kk]);
        const short8 b1 = *(const short8*)(&sW[(1*16 + l16) * SW_STRIDE + kk]);
        const short8 b2 = *(const short8*)(&sW[(2*16 + l16) * SW_STRIDE + kk]);
        const short8 b3 = *(const short8*)(&sW[(3*16 + l16) * SW_STRIDE + kk]);
        const int ci = h * 32 + quad * 8;
        short8 a0 = *(const short8*)(&sIn[(m0 + tap) * FSIN_STRIDE + ci]);
        short8 a1 = *(const short8*)(&sIn[(m1 + tap) * FSIN_STRIDE + ci]);
        if (!msk0) a0 = zero8;
        if (!msk1) a1 = zero8;
        acc[0][0] = __builtin_amdgcn_mfma_f32_16x16x32_bf16(a0,b0,acc[0][0],0,0,0);
        acc[0][1] = __builtin_amdgcn_mfma_f32_16x16x32_bf16(a0,b1,acc[0][1],0,0,0);
        acc[0][2] = __builtin_amdgcn_mfma_f32_16x16x32_bf16(a0,b2,acc[0][2],0,0,0);
        acc[0][3] = __builtin_amdgcn_mfma_f32_16x16x32_bf16(a0,b3,acc[0][3],0,0,0);
        acc[1][0] = __builtin_amdgcn_mfma_f32_16x16x32_bf16(a1,b0,acc[1][0],0,0,0);
        acc[1][1] = __builtin_amdgcn_mfma_f32_16x16x32_bf16(a1,b1,acc[1][1],0,0,0);
        acc[1][2] = __builtin_amdgcn_mfma_f32_16x16x32_bf16(a1,b2,acc[1][2],0,0,0);
        acc[1][3] = __builtin_amdgcn_mfma_f32_16x16x32_bf16(a1,b3,acc[1][3],0,0,0);
      }
    }
    #pragma unroll
    for (int mm = 0; mm < 2; ++mm) {
      const int lrow = l0 + wave * 32 + mm * 16 + quad * 4;
      #pragma unroll
      for (int reg = 0; reg < 4; ++reg) {
        float* orow = gout + ((size_t)(bL + lrow + reg) * NG + g) * OPG;
        #pragma unroll
        for (int nt = 0; nt < 4; ++nt)
          orow[nt * 16 + l16] = acc[mm][nt][reg];
      }
    }
  }
}

extern "C" void kernel_launch(void* const* d_in, const int* in_sizes, int n_in,
                              void* d_out, int out_size, void* d_ws, size_t ws_size,
                              hipStream_t stream) {
  (void)in_sizes; (void)n_in; (void)out_size;
  const float* gin  = (const float*)d_in[0];
  const int*   gpos = (const int*)d_in[1];
  const float* gwt  = (const float*)d_in[2];
  float*       gout = (float*)d_out;

  if (ws_size >= WFRAG_BYTES + MASK_BYTES) {
    unsigned short* wfrag = (unsigned short*)d_ws;
    unsigned char*  gmask = (unsigned char*)d_ws + WFRAG_BYTES;
    hipLaunchKernelGGL(wprep, dim3(160), dim3(256), 0, stream, gwt, wfrag);
    hipLaunchKernelGGL(mprep, dim3(64), dim3(256), 0, stream, gpos, gmask);
    dim3 grid(LSEQ / (ROWS * CH), NG, 4);   // 16 x 16 x 4 = 1024 blocks
    hipLaunchKernelGGL(mconv_main2, grid, dim3(256), 0, stream,
                       gin, gmask, wfrag, gout);
  } else if (ws_size >= WFRAG_BYTES) {
    unsigned short* wfrag = (unsigned short*)d_ws;
    hipLaunchKernelGGL(wprep, dim3(160), dim3(256), 0, stream, gwt, wfrag);
    dim3 grid(LSEQ / ROWS, NG, 4);
    hipLaunchKernelGGL(mconv_main, grid, dim3(256), 0, stream,
                       gin, gpos, wfrag, gout);
  } else {
    dim3 grid(LSEQ / fb::ROWS_PER_BLOCK, NG, 4);
    hipLaunchKernelGGL(mconv_f32_mfma, grid, dim3(256), 0, stream,
                       gin, gpos, gwt, gout);
  }
}